// Round 3
// baseline (169.862 us; speedup 1.0000x reference)
//
#include <hip/hip_runtime.h>
#include <hip/hip_bf16.h>
#include <math.h>

#define B 8
#define N 2048
#define F_IN 128
#define F_OUT 64
#define ALPHA 0.2f

typedef _Float16 half8 __attribute__((ext_vector_type(8)));
typedef float f32x4 __attribute__((ext_vector_type(4)));

// ---------------------------------------------------------------------------
// Kernel 1: adj -> bitmask (u32 words). bits[i*64 + j/32] bit (j%32) = adj[i][j]>0
// ---------------------------------------------------------------------------
__global__ __launch_bounds__(256) void bitmask_kernel(
    const float* __restrict__ adj, unsigned* __restrict__ bits)
{
    const int i = blockIdx.x;
    const int tid = threadIdx.x;
    const int lane = tid & 63;
    const int w = tid >> 6;
    const float* row = adj + (size_t)i * N;
#pragma unroll
    for (int jt = 0; jt < 8; ++jt) {
        float v = row[jt * 256 + tid];
        unsigned long long m = __ballot(v > 0.f);
        if (lane == 0) {
            bits[i * 64 + jt * 8 + w * 2]     = (unsigned)m;
            bits[i * 64 + jt * 8 + w * 2 + 1] = (unsigned)(m >> 32);
        }
    }
}

// ---------------------------------------------------------------------------
// Kernel 2: WhT[b][f][j] (f16) = (h @ W)^T, plus f = Wh.a1, g = Wh.a2 (fp32)
// ---------------------------------------------------------------------------
__global__ __launch_bounds__(256) void wh_fg_t_kernel(
    const float* __restrict__ h, const float* __restrict__ W,
    const float* __restrict__ a, _Float16* __restrict__ WhT,
    float* __restrict__ fv, float* __restrict__ gv)
{
    const int tid  = threadIdx.x;
    const int w    = tid >> 6;
    const int lane = tid & 63;

    __shared__ float Ws[F_IN * F_OUT];    // 32 KB
    __shared__ float hs[16 * F_IN];       // 8 KB
    __shared__ float t32[16 * 65];        // transpose buffer (pad 65)

    const float4* W4 = (const float4*)W;
    float4* Ws4 = (float4*)Ws;
#pragma unroll
    for (int q = 0; q < 8; ++q)
        Ws4[q * 256 + tid] = W4[q * 256 + tid];

    const float4* h4 = (const float4*)h;
    float4* hs4 = (float4*)hs;
    const size_t hbase = (size_t)blockIdx.x * 512;
#pragma unroll
    for (int q = 0; q < 2; ++q)
        hs4[q * 256 + tid] = h4[hbase + q * 256 + tid];

    const float av1 = a[lane];
    const float av2 = a[F_OUT + lane];
    __syncthreads();

    float acc[4] = {0.f, 0.f, 0.f, 0.f};
    const int lr0 = w * 4;
    for (int k4 = 0; k4 < F_IN / 4; ++k4) {
        float4 hv[4];
#pragma unroll
        for (int rr = 0; rr < 4; ++rr)
            hv[rr] = hs4[(lr0 + rr) * (F_IN / 4) + k4];
#pragma unroll
        for (int kk = 0; kk < 4; ++kk) {
            float wv = Ws[(k4 * 4 + kk) * F_OUT + lane];
#pragma unroll
            for (int rr = 0; rr < 4; ++rr)
                acc[rr] += ((const float*)&hv[rr])[kk] * wv;
        }
    }

    const int b     = blockIdx.x >> 7;
    const int j0    = (blockIdx.x & 127) * 16;
    const size_t gr0 = (size_t)b * N + j0 + lr0;

#pragma unroll
    for (int rr = 0; rr < 4; ++rr) {
        t32[(lr0 + rr) * 65 + lane] = acc[rr];
        float fp = acc[rr] * av1;
        float gp = acc[rr] * av2;
#pragma unroll
        for (int off = 32; off >= 1; off >>= 1) {
            fp += __shfl_down(fp, off, 64);
            gp += __shfl_down(gp, off, 64);
        }
        if (lane == 0) {
            fv[gr0 + rr] = fp;
            gv[gr0 + rr] = gp;
        }
    }
    __syncthreads();

    const int f  = tid >> 2;
    const int jq = tid & 3;
    union { _Float16 h[4]; ushort4 u; } pk;
#pragma unroll
    for (int t = 0; t < 4; ++t)
        pk.h[t] = (_Float16)t32[(jq * 4 + t) * 65 + f];
    *(ushort4*)(WhT + (size_t)b * F_OUT * N + (size_t)f * N + j0 + jq * 4) = pk.u;
}

// ---------------------------------------------------------------------------
// Kernel 3: aggregation via MFMA, 16 i-rows/block, 4 waves (256 thr).
// Double-buffered LDS, ONE barrier per k-tile: prefetch next WhT slab into
// registers + compute next P tile (VALU) while MFMAs consume current buffer.
// ---------------------------------------------------------------------------
#define PSTR 136   // f16 row stride (pad 128+8): uniform 8 lanes/bank
#define KT   (N / 128)

__global__ __launch_bounds__(256) void attn_mfma_kernel(
    const _Float16* __restrict__ WhT, const float* __restrict__ fv,
    const float* __restrict__ gv, const unsigned* __restrict__ bits,
    float* __restrict__ out)
{
    const int i0 = blockIdx.x * 16;
    const int b  = blockIdx.y;
    const int tid  = threadIdx.x;
    const int lane = tid & 63;
    const int wsl  = tid >> 6;     // wave = feature slice

    __shared__ float    gs[N];                 // 8 KB
    __shared__ float    fs[16];
    __shared__ float    ms[16];
    __shared__ float    rs[16];
    __shared__ unsigned mws[16 * 64];          // 4 KB
    __shared__ _Float16 WhTs[2][64 * PSTR];    // 34 KB
    __shared__ _Float16 Ps[2][16 * PSTR];      // 8.5 KB

    // global staging role: thread stages feature row fwh, 32-f16 segment seg
    const int fwh = tid >> 2;      // 0..63
    const int seg = tid & 3;       // 0..3
    const _Float16* whbase = WhT + (size_t)b * F_OUT * N + (size_t)fwh * N + seg * 32;

    // issue tile-0 global loads immediately (latency hides under staging+rowmax)
    float4 wv[4];
#pragma unroll
    for (int q = 0; q < 4; ++q)
        wv[q] = *(const float4*)(whbase + q * 8);

    // stage g row, f values, mask words
    const float4* g4 = (const float4*)(gv + (size_t)b * N);
    ((float4*)gs)[tid]       = g4[tid];
    ((float4*)gs)[tid + 256] = g4[tid + 256];
    if (tid < 16) fs[tid] = fv[(size_t)b * N + i0 + tid];
    ((uint4*)mws)[tid] = ((const uint4*)(bits + (size_t)(i0 + (tid >> 4)) * 64))[tid & 15];
    __syncthreads();

    const int ii = tid >> 4;        // i slot
    const int jj = tid & 15;        // j group

    // per-row masked max of g (leaky monotone => rowmax = leaky(fi + max g))
    float gmax = -INFINITY;
#pragma unroll
    for (int t = 0; t < 4; ++t) {
        unsigned mw = mws[ii * 64 + jj * 4 + t];
        const int jb = jj * 128 + t * 32;
        while (mw) {
            int bit = __builtin_ctz(mw);
            gmax = fmaxf(gmax, gs[jb + bit]);
            mw &= mw - 1;
        }
    }
#pragma unroll
    for (int off = 8; off >= 1; off >>= 1)
        gmax = fmaxf(gmax, __shfl_down(gmax, off, 16));
    if (jj == 0) {
        float m = fs[ii] + gmax;
        ms[ii] = (m > 0.f) ? m : ALPHA * m;
    }
    __syncthreads();

    const float fi = fs[ii];
    const float mi = ms[ii];
    const int mrow = lane & 15;
    const int quad = lane >> 4;

    f32x4 acc = {0.f, 0.f, 0.f, 0.f};
    float psum = 0.f;

    // ---- prologue: fill buffer 0 (P tile 0 + WhT slab 0) ----
    {
        const int jA = jj * 8;
        unsigned mbits = (mws[ii * 64 + (jj >> 2)] >> ((jj & 3) * 8)) & 0xFFu;
        half8 pk;
#pragma unroll
        for (int t = 0; t < 8; ++t) {
            float s = fi + gs[jA + t];
            s = (s > 0.f) ? s : ALPHA * s;
            float p = ((mbits >> t) & 1u) ? __expf(s - mi) : 0.f;
            pk[t] = (_Float16)p;
            psum += (float)pk[t];
        }
        *(half8*)(&Ps[0][ii * PSTR + jj * 8]) = pk;
#pragma unroll
        for (int q = 0; q < 4; ++q)
            *(float4*)(&WhTs[0][fwh * PSTR + seg * 32 + q * 8]) = wv[q];
    }
    __syncthreads();

    // ---- main loop: one barrier per tile, double-buffered ----
    for (int kt = 0; kt < KT; ++kt) {
        const int cur = kt & 1;

        if (kt + 1 < KT) {
            // prefetch next WhT slab into registers (latency covered below)
#pragma unroll
            for (int q = 0; q < 4; ++q)
                wv[q] = *(const float4*)(whbase + (kt + 1) * 128 + q * 8);

            // compute next P tile (pure VALU, overlaps the loads)
            const int j0n = (kt + 1) * 128;
            const int jA = j0n + jj * 8;
            unsigned mbits = (mws[ii * 64 + (j0n >> 5) + (jj >> 2)] >> ((jj & 3) * 8)) & 0xFFu;
            half8 pk;
#pragma unroll
            for (int t = 0; t < 8; ++t) {
                float s = fi + gs[jA + t];
                s = (s > 0.f) ? s : ALPHA * s;
                float p = ((mbits >> t) & 1u) ? __expf(s - mi) : 0.f;
                pk[t] = (_Float16)p;
                psum += (float)pk[t];
            }
            *(half8*)(&Ps[cur ^ 1][ii * PSTR + jj * 8]) = pk;
        }

        // MFMA on current buffer
#pragma unroll
        for (int q = 0; q < 4; ++q) {
            half8 aF = *(const half8*)(&Ps[cur][mrow * PSTR + q * 32 + quad * 8]);
            half8 bF = *(const half8*)(&WhTs[cur][(wsl * 16 + mrow) * PSTR + q * 32 + quad * 8]);
            acc = __builtin_amdgcn_mfma_f32_16x16x32_f16(aF, bF, acc, 0, 0, 0);
        }

        if (kt + 1 < KT) {
            // land the prefetched slab into the alternate buffer
#pragma unroll
            for (int q = 0; q < 4; ++q)
                *(float4*)(&WhTs[cur ^ 1][fwh * PSTR + seg * 32 + q * 8]) = wv[q];
        }
        __syncthreads();
    }

    // denominator: reduce psum over the 16 threads sharing ii
#pragma unroll
    for (int off = 8; off >= 1; off >>= 1)
        psum += __shfl_down(psum, off, 16);
    if (jj == 0) rs[ii] = psum;
    __syncthreads();

    // epilogue: D row = quad*4+reg, col = mrow
#pragma unroll
    for (int reg = 0; reg < 4; ++reg) {
        int irow = quad * 4 + reg;
        float v = acc[reg] / rs[irow];
        out[((size_t)b * N + i0 + irow) * F_OUT + wsl * 16 + mrow] = v;
    }
}

extern "C" void kernel_launch(void* const* d_in, const int* in_sizes, int n_in,
                              void* d_out, int out_size, void* d_ws, size_t ws_size,
                              hipStream_t stream) {
    const float* h   = (const float*)d_in[0];
    const float* adj = (const float*)d_in[1];
    const float* W   = (const float*)d_in[2];
    const float* a   = (const float*)d_in[3];
    float* out = (float*)d_out;

    char* ws = (char*)d_ws;
    _Float16* WhT = (_Float16*)ws;                        // 2 MB
    float* fv = (float*)(ws + (size_t)B * F_OUT * N * 2); // 64 KB
    float* gv = fv + (size_t)B * N;                       // 64 KB
    unsigned* bits = (unsigned*)(gv + (size_t)B * N);     // 512 KB

    bitmask_kernel<<<dim3(N), 256, 0, stream>>>(adj, bits);
    wh_fg_t_kernel<<<dim3(B * N / 16), 256, 0, stream>>>(h, W, a, WhT, fv, gv);
    attn_mfma_kernel<<<dim3(N / 16, B), 256, 0, stream>>>(WhT, fv, gv, bits, out);
}

// Round 4
// 134.552 us; speedup vs baseline: 1.2624x; 1.2624x over previous
//
#include <hip/hip_runtime.h>
#include <hip/hip_bf16.h>
#include <math.h>

#define B 8
#define N 2048
#define F_IN 128
#define F_OUT 64
#define ALPHA 0.2f

typedef _Float16 half8 __attribute__((ext_vector_type(8)));
typedef float f32x4 __attribute__((ext_vector_type(4)));

// ---------------------------------------------------------------------------
// Kernel 1: adj -> bitmask (u32 words). bits[i*64 + j/32] bit (j%32) = adj[i][j]>0
// ---------------------------------------------------------------------------
__global__ __launch_bounds__(256) void bitmask_kernel(
    const float* __restrict__ adj, unsigned* __restrict__ bits)
{
    const int i = blockIdx.x;
    const int tid = threadIdx.x;
    const int lane = tid & 63;
    const int w = tid >> 6;
    const float* row = adj + (size_t)i * N;
#pragma unroll
    for (int jt = 0; jt < 8; ++jt) {
        float v = row[jt * 256 + tid];
        unsigned long long m = __ballot(v > 0.f);
        if (lane == 0) {
            bits[i * 64 + jt * 8 + w * 2]     = (unsigned)m;
            bits[i * 64 + jt * 8 + w * 2 + 1] = (unsigned)(m >> 32);
        }
    }
}

// ---------------------------------------------------------------------------
// Kernel 2: WhT[b][f][j] (f16) = (h @ W)^T, plus f = Wh.a1, g = Wh.a2 (fp32)
// ---------------------------------------------------------------------------
__global__ __launch_bounds__(256) void wh_fg_t_kernel(
    const float* __restrict__ h, const float* __restrict__ W,
    const float* __restrict__ a, _Float16* __restrict__ WhT,
    float* __restrict__ fv, float* __restrict__ gv)
{
    const int tid  = threadIdx.x;
    const int w    = tid >> 6;
    const int lane = tid & 63;

    __shared__ float Ws[F_IN * F_OUT];    // 32 KB
    __shared__ float hs[16 * F_IN];       // 8 KB
    __shared__ float t32[16 * 65];        // transpose buffer (pad 65)

    const float4* W4 = (const float4*)W;
    float4* Ws4 = (float4*)Ws;
#pragma unroll
    for (int q = 0; q < 8; ++q)
        Ws4[q * 256 + tid] = W4[q * 256 + tid];

    const float4* h4 = (const float4*)h;
    float4* hs4 = (float4*)hs;
    const size_t hbase = (size_t)blockIdx.x * 512;
#pragma unroll
    for (int q = 0; q < 2; ++q)
        hs4[q * 256 + tid] = h4[hbase + q * 256 + tid];

    const float av1 = a[lane];
    const float av2 = a[F_OUT + lane];
    __syncthreads();

    float acc[4] = {0.f, 0.f, 0.f, 0.f};
    const int lr0 = w * 4;
    for (int k4 = 0; k4 < F_IN / 4; ++k4) {
        float4 hv[4];
#pragma unroll
        for (int rr = 0; rr < 4; ++rr)
            hv[rr] = hs4[(lr0 + rr) * (F_IN / 4) + k4];
#pragma unroll
        for (int kk = 0; kk < 4; ++kk) {
            float wv = Ws[(k4 * 4 + kk) * F_OUT + lane];
#pragma unroll
            for (int rr = 0; rr < 4; ++rr)
                acc[rr] += ((const float*)&hv[rr])[kk] * wv;
        }
    }

    const int b     = blockIdx.x >> 7;
    const int j0    = (blockIdx.x & 127) * 16;
    const size_t gr0 = (size_t)b * N + j0 + lr0;

#pragma unroll
    for (int rr = 0; rr < 4; ++rr) {
        t32[(lr0 + rr) * 65 + lane] = acc[rr];
        float fp = acc[rr] * av1;
        float gp = acc[rr] * av2;
#pragma unroll
        for (int off = 32; off >= 1; off >>= 1) {
            fp += __shfl_down(fp, off, 64);
            gp += __shfl_down(gp, off, 64);
        }
        if (lane == 0) {
            fv[gr0 + rr] = fp;
            gv[gr0 + rr] = gp;
        }
    }
    __syncthreads();

    const int f  = tid >> 2;
    const int jq = tid & 3;
    union { _Float16 h[4]; ushort4 u; } pk;
#pragma unroll
    for (int t = 0; t < 4; ++t)
        pk.h[t] = (_Float16)t32[(jq * 4 + t) * 65 + f];
    *(ushort4*)(WhT + (size_t)b * F_OUT * N + (size_t)f * N + j0 + jq * 4) = pk.u;
}

// ---------------------------------------------------------------------------
// Kernel 3: barrier-free MFMA aggregation.
// 16 i-rows/block, 4 waves. Wave wsl owns k-tiles [wsl*4, wsl*4+4) (512 j's):
// computes P in registers (exp once, no LDS P), loads B-fragments directly
// from L2-resident WhT in MFMA layout, accumulates partial C over all 64
// features. Cross-wave reduction of C and row-sums at the end via LDS.
// ---------------------------------------------------------------------------
#define MSTR 68   // mws row stride (u32): 16 rows -> 2-way banks max

__global__ __launch_bounds__(256, 4) void attn_mfma_kernel(
    const _Float16* __restrict__ WhT, const float* __restrict__ fv,
    const float* __restrict__ gv, const unsigned* __restrict__ bits,
    float* __restrict__ out)
{
    const int i0 = blockIdx.x * 16;
    const int b  = blockIdx.y;
    const int tid  = threadIdx.x;
    const int lane = tid & 63;
    const int wsl  = tid >> 6;     // wave: owns k-tiles wsl*4 .. wsl*4+3
    const int mrow = lane & 15;
    const int quad = lane >> 4;

    __shared__ __align__(16) float    gs[N];             // 8 KB
    __shared__ float    fs[16];
    __shared__ float    ms[16];
    __shared__ __align__(16) unsigned mws[16 * MSTR];    // 4.25 KB
    __shared__ float    redacc[4 * 16 * MSTR];           // 17 KB  [wave][row][col]
    __shared__ float    rsp[4 * 16];                     // per-wave row sums

    // ---- stage g row, f values, mask words (padded stride) ----
    const float4* g4 = (const float4*)(gv + (size_t)b * N);
    ((float4*)gs)[tid]       = g4[tid];
    ((float4*)gs)[tid + 256] = g4[tid + 256];
    if (tid < 16) fs[tid] = fv[(size_t)b * N + i0 + tid];
    {
        const int i  = tid >> 4;
        const int w4 = (tid & 15) * 4;
        *(uint4*)&mws[i * MSTR + w4] =
            *(const uint4*)&bits[(size_t)(i0 + i) * 64 + w4];
    }
    __syncthreads();

    // ---- per-row masked max of g (leaky monotone => rowmax = leaky(f + max g)) ----
    {
        const int ii = tid >> 4;
        const int jj = tid & 15;
        float gmax = -INFINITY;
#pragma unroll
        for (int t = 0; t < 4; ++t) {
            unsigned mw = mws[ii * MSTR + jj * 4 + t];
            const int jb = jj * 128 + t * 32;
            while (mw) {
                int bit = __builtin_ctz(mw);
                gmax = fmaxf(gmax, gs[jb + bit]);
                mw &= mw - 1;
            }
        }
#pragma unroll
        for (int off = 8; off >= 1; off >>= 1)
            gmax = fmaxf(gmax, __shfl_down(gmax, off, 16));
        if (jj == 0) {
            float m = fs[ii] + gmax;
            ms[ii] = (m > 0.f) ? m : ALPHA * m;
        }
    }
    __syncthreads();

    const float fi = fs[mrow];
    const float mi = ms[mrow];
    const _Float16* whb = WhT + (size_t)b * F_OUT * N;

    f32x4 acc0 = {0.f,0.f,0.f,0.f}, acc1 = {0.f,0.f,0.f,0.f};
    f32x4 acc2 = {0.f,0.f,0.f,0.f}, acc3 = {0.f,0.f,0.f,0.f};
    float psum = 0.f;

    // ---- main loop: 4 k-tiles per wave, NO barriers ----
    for (int m = 0; m < 4; ++m) {
        const int j0 = (wsl * 4 + m) * 128;
        const uint4 mwv = *(const uint4*)&mws[mrow * MSTR + (j0 >> 5)];
#pragma unroll
        for (int q = 0; q < 4; ++q) {
            const int jb = j0 + q * 32 + quad * 8;

            // B fragments for all 4 feature groups (global, L2-hit, MFMA layout)
            half8 b0 = *(const half8*)(whb + (size_t)(mrow)      * N + jb);
            half8 b1 = *(const half8*)(whb + (size_t)(16 + mrow) * N + jb);
            half8 b2 = *(const half8*)(whb + (size_t)(32 + mrow) * N + jb);
            half8 b3 = *(const half8*)(whb + (size_t)(48 + mrow) * N + jb);

            // P fragment in registers (this lane: row mrow, cols jb..jb+7)
            const unsigned mword = (q == 0) ? mwv.x : (q == 1) ? mwv.y
                                 : (q == 2) ? mwv.z : mwv.w;
            const unsigned mbyte = (mword >> (quad * 8)) & 0xFFu;
            float4 ga = *(const float4*)&gs[jb];
            float4 gb = *(const float4*)&gs[jb + 4];
            half8 aF;
#pragma unroll
            for (int t = 0; t < 8; ++t) {
                float g = (t < 4) ? ((const float*)&ga)[t]
                                  : ((const float*)&gb)[t - 4];
                float s = fi + g;
                s = fmaxf(s, ALPHA * s);                       // leaky relu
                float p = ((mbyte >> t) & 1u) ? __expf(s - mi) : 0.f;
                _Float16 ph = (_Float16)p;
                aF[t] = ph;
                psum += (float)ph;
            }

            acc0 = __builtin_amdgcn_mfma_f32_16x16x32_f16(aF, b0, acc0, 0, 0, 0);
            acc1 = __builtin_amdgcn_mfma_f32_16x16x32_f16(aF, b1, acc1, 0, 0, 0);
            acc2 = __builtin_amdgcn_mfma_f32_16x16x32_f16(aF, b2, acc2, 0, 0, 0);
            acc3 = __builtin_amdgcn_mfma_f32_16x16x32_f16(aF, b3, acc3, 0, 0, 0);
        }
    }

    // ---- per-wave row-sum: lanes sharing mrow (quads) hold disjoint j's ----
    psum += __shfl_xor(psum, 16, 64);
    psum += __shfl_xor(psum, 32, 64);
    if (lane < 16) rsp[wsl * 16 + lane] = psum;

    // ---- write partial C to LDS: C layout row = quad*4+reg, col = mrow ----
#pragma unroll
    for (int reg = 0; reg < 4; ++reg) {
        const int row = quad * 4 + reg;
        float* dst = &redacc[(wsl * 16 + row) * MSTR];
        dst[mrow]      = acc0[reg];
        dst[16 + mrow] = acc1[reg];
        dst[32 + mrow] = acc2[reg];
        dst[48 + mrow] = acc3[reg];
    }
    __syncthreads();

    // ---- cross-wave reduce + normalize + store (coalesced) ----
    const int col = tid & 63;
    const int r4  = tid >> 6;
#pragma unroll
    for (int rr = 0; rr < 4; ++rr) {
        const int row = r4 * 4 + rr;
        float sum = redacc[(row) * MSTR + col]
                  + redacc[(16 + row) * MSTR + col]
                  + redacc[(32 + row) * MSTR + col]
                  + redacc[(48 + row) * MSTR + col];
        float den = rsp[row] + rsp[16 + row] + rsp[32 + row] + rsp[48 + row];
        out[((size_t)b * N + i0 + row) * F_OUT + col] = sum / den;
    }
}

extern "C" void kernel_launch(void* const* d_in, const int* in_sizes, int n_in,
                              void* d_out, int out_size, void* d_ws, size_t ws_size,
                              hipStream_t stream) {
    const float* h   = (const float*)d_in[0];
    const float* adj = (const float*)d_in[1];
    const float* W   = (const float*)d_in[2];
    const float* a   = (const float*)d_in[3];
    float* out = (float*)d_out;

    char* ws = (char*)d_ws;
    _Float16* WhT = (_Float16*)ws;                        // 2 MB
    float* fv = (float*)(ws + (size_t)B * F_OUT * N * 2); // 64 KB
    float* gv = fv + (size_t)B * N;                       // 64 KB
    unsigned* bits = (unsigned*)(gv + (size_t)B * N);     // 512 KB

    bitmask_kernel<<<dim3(N), 256, 0, stream>>>(adj, bits);
    wh_fg_t_kernel<<<dim3(B * N / 16), 256, 0, stream>>>(h, W, a, WhT, fv, gv);
    attn_mfma_kernel<<<dim3(N / 16, B), 256, 0, stream>>>(WhT, fv, gv, bits, out);
}

// Round 5
// 120.602 us; speedup vs baseline: 1.4084x; 1.1157x over previous
//
#include <hip/hip_runtime.h>
#include <hip/hip_bf16.h>
#include <math.h>

#define B 8
#define N 2048
#define F_IN 128
#define F_OUT 64
#define ALPHA 0.2f

typedef _Float16 half8 __attribute__((ext_vector_type(8)));
typedef float f32x4 __attribute__((ext_vector_type(4)));

// ---------------------------------------------------------------------------
// Kernel 1: adj -> bitmask (u32 words). bits[i*64 + j/32] bit (j%32) = adj[i][j]>0
// ---------------------------------------------------------------------------
__global__ __launch_bounds__(256) void bitmask_kernel(
    const float* __restrict__ adj, unsigned* __restrict__ bits)
{
    const int i = blockIdx.x;
    const int tid = threadIdx.x;
    const int lane = tid & 63;
    const int w = tid >> 6;
    const float* row = adj + (size_t)i * N;
#pragma unroll
    for (int jt = 0; jt < 8; ++jt) {
        float v = row[jt * 256 + tid];
        unsigned long long m = __ballot(v > 0.f);
        if (lane == 0) {
            bits[i * 64 + jt * 8 + w * 2]     = (unsigned)m;
            bits[i * 64 + jt * 8 + w * 2 + 1] = (unsigned)(m >> 32);
        }
    }
}

// ---------------------------------------------------------------------------
// Kernel 2: Wpack = (h @ W)^T pre-swizzled into MFMA B-fragment order:
//   Wpack[((b*16+m)*4+q)*4+fg][lane(quad*16+fr)][8 halfs]   (m=j/128, q, quad)
// so kernel 3 loads fragments as base + lane*16B (fully coalesced).
// Also f = Wh.a1, g = Wh.a2 (fp32).
// ---------------------------------------------------------------------------
__global__ __launch_bounds__(256) void wh_fg_t_kernel(
    const float* __restrict__ h, const float* __restrict__ W,
    const float* __restrict__ a, _Float16* __restrict__ Wpack,
    float* __restrict__ fv, float* __restrict__ gv)
{
    const int tid  = threadIdx.x;
    const int w    = tid >> 6;
    const int lane = tid & 63;

    __shared__ float Ws[F_IN * F_OUT];    // 32 KB
    __shared__ float hs[16 * F_IN];       // 8 KB
    __shared__ float t32[16 * 65];        // transpose buffer (pad 65)

    const float4* W4 = (const float4*)W;
    float4* Ws4 = (float4*)Ws;
#pragma unroll
    for (int q = 0; q < 8; ++q)
        Ws4[q * 256 + tid] = W4[q * 256 + tid];

    const float4* h4 = (const float4*)h;
    float4* hs4 = (float4*)hs;
    const size_t hbase = (size_t)blockIdx.x * 512;
#pragma unroll
    for (int q = 0; q < 2; ++q)
        hs4[q * 256 + tid] = h4[hbase + q * 256 + tid];

    const float av1 = a[lane];
    const float av2 = a[F_OUT + lane];
    __syncthreads();

    float acc[4] = {0.f, 0.f, 0.f, 0.f};
    const int lr0 = w * 4;
    for (int k4 = 0; k4 < F_IN / 4; ++k4) {
        float4 hv[4];
#pragma unroll
        for (int rr = 0; rr < 4; ++rr)
            hv[rr] = hs4[(lr0 + rr) * (F_IN / 4) + k4];
#pragma unroll
        for (int kk = 0; kk < 4; ++kk) {
            float wv = Ws[(k4 * 4 + kk) * F_OUT + lane];
#pragma unroll
            for (int rr = 0; rr < 4; ++rr)
                acc[rr] += ((const float*)&hv[rr])[kk] * wv;
        }
    }

    const int b     = blockIdx.x >> 7;
    const int j0    = (blockIdx.x & 127) * 16;
    const size_t gr0 = (size_t)b * N + j0 + lr0;

#pragma unroll
    for (int rr = 0; rr < 4; ++rr) {
        t32[(lr0 + rr) * 65 + lane] = acc[rr];
        float fp = acc[rr] * av1;
        float gp = acc[rr] * av2;
#pragma unroll
        for (int off = 32; off >= 1; off >>= 1) {
            fp += __shfl_down(fp, off, 64);
            gp += __shfl_down(gp, off, 64);
        }
        if (lane == 0) {
            fv[gr0 + rr] = fp;
            gv[gr0 + rr] = gp;
        }
    }
    __syncthreads();

    // packed fragment-order write: thread owns feature f, j's jj0..jj0+3
    const int f   = tid >> 2;      // 0..63
    const int jq  = tid & 3;       // 0..3
    const int jj0 = j0 + jq * 4;
    const int m    = jj0 >> 7;
    const int q    = (jj0 >> 5) & 3;
    const int quad = (jj0 >> 3) & 3;
    const int e    = jj0 & 7;      // 0 or 4
    union { _Float16 h[4]; ushort4 u; } pk;
#pragma unroll
    for (int t = 0; t < 4; ++t)
        pk.h[t] = (_Float16)t32[(jq * 4 + t) * 65 + f];
    const size_t base =
        ((((size_t)b * 16 + m) * 4 + q) * 4 + (f >> 4)) * 512
        + (size_t)(quad * 16 + (f & 15)) * 8 + e;
    *(ushort4*)(Wpack + base) = pk.u;
}

// ---------------------------------------------------------------------------
// Kernel 3: barrier-free MFMA aggregation, 32 i-rows/block (2 stacked 16-row
// tiles), 4 waves. Wave wsl owns k-tiles [wsl*4, wsl*4+4) (512 j's): computes
// P in registers (exp once per (row,j)), loads B-fragments coalesced from the
// pre-swizzled Wpack (L2-resident), 8 MFMAs per 4 loads. Cross-wave reduction
// of partial C and row-sums at the end via LDS.
// ---------------------------------------------------------------------------
#define MSTR 68   // mws row stride (u32)
#define RSTR 68   // redacc row stride (f32)

__global__ __launch_bounds__(256) void attn_mfma_kernel(
    const _Float16* __restrict__ Wpack, const float* __restrict__ fv,
    const float* __restrict__ gv, const unsigned* __restrict__ bits,
    float* __restrict__ out)
{
    const int i0 = blockIdx.x * 32;
    const int b  = blockIdx.y;
    const int tid  = threadIdx.x;
    const int lane = tid & 63;
    const int wsl  = tid >> 6;     // wave: owns k-tiles wsl*4 .. wsl*4+3
    const int mrow = lane & 15;
    const int quad = lane >> 4;

    __shared__ __align__(16) float    gs[N];             // 8 KB
    __shared__ float    fs[32];
    __shared__ float    ms[32];
    __shared__ __align__(16) unsigned mws[32 * MSTR];    // 8.5 KB
    __shared__ float    redacc[4 * 32 * RSTR];           // 34.8 KB [wave][row][col]
    __shared__ float    rsp[4 * 32];                     // per-wave row sums

    // ---- stage g row, f values, mask words (padded stride) ----
    const float4* g4 = (const float4*)(gv + (size_t)b * N);
    ((float4*)gs)[tid]       = g4[tid];
    ((float4*)gs)[tid + 256] = g4[tid + 256];
    if (tid < 32) fs[tid] = fv[(size_t)b * N + i0 + tid];
#pragma unroll
    for (int s = 0; s < 2; ++s) {
        const int idx = tid + s * 256;
        const int i   = idx >> 4;
        const int w4  = (idx & 15) * 4;
        *(uint4*)&mws[i * MSTR + w4] =
            *(const uint4*)&bits[(size_t)(i0 + i) * 64 + w4];
    }
    __syncthreads();

    // ---- per-row masked max of g (leaky monotone => rowmax = leaky(f+max g)) ----
#pragma unroll
    for (int rr = 0; rr < 2; ++rr) {
        const int ii = rr * 16 + (tid >> 4);
        const int jj = tid & 15;
        float gmax = -INFINITY;
#pragma unroll
        for (int t = 0; t < 4; ++t) {
            unsigned mw = mws[ii * MSTR + jj * 4 + t];
            const int jb = jj * 128 + t * 32;
            while (mw) {
                int bit = __builtin_ctz(mw);
                gmax = fmaxf(gmax, gs[jb + bit]);
                mw &= mw - 1;
            }
        }
#pragma unroll
        for (int off = 8; off >= 1; off >>= 1)
            gmax = fmaxf(gmax, __shfl_down(gmax, off, 16));
        if (jj == 0) {
            float m = fs[ii] + gmax;
            ms[ii] = (m > 0.f) ? m : ALPHA * m;
        }
    }
    __syncthreads();

    const float fi0 = fs[mrow],      mi0 = ms[mrow];
    const float fi1 = fs[16 + mrow], mi1 = ms[16 + mrow];
    const _Float16* wpb = Wpack + (size_t)b * 131072;   // 16*4*4*512

    f32x4 a00 = {0,0,0,0}, a01 = {0,0,0,0}, a02 = {0,0,0,0}, a03 = {0,0,0,0};
    f32x4 a10 = {0,0,0,0}, a11 = {0,0,0,0}, a12 = {0,0,0,0}, a13 = {0,0,0,0};
    float psum0 = 0.f, psum1 = 0.f;

    // ---- main loop: 4 k-tiles per wave, NO barriers ----
    for (int mm = 0; mm < 4; ++mm) {
        const int m  = wsl * 4 + mm;
        const uint4 mv0 = *(const uint4*)&mws[mrow * MSTR + m * 4];
        const uint4 mv1 = *(const uint4*)&mws[(16 + mrow) * MSTR + m * 4];
#pragma unroll
        for (int q = 0; q < 4; ++q) {
            const int jb = m * 128 + q * 32 + quad * 8;
            const _Float16* tb = wpb + (size_t)(m * 4 + q) * 2048 + lane * 8;

            // B fragments, coalesced (lane-contiguous 16B)
            half8 b0 = *(const half8*)(tb);
            half8 b1 = *(const half8*)(tb + 512);
            half8 b2 = *(const half8*)(tb + 1024);
            half8 b3 = *(const half8*)(tb + 1536);

            const unsigned w0 = (q == 0) ? mv0.x : (q == 1) ? mv0.y
                               : (q == 2) ? mv0.z : mv0.w;
            const unsigned w1 = (q == 0) ? mv1.x : (q == 1) ? mv1.y
                               : (q == 2) ? mv1.z : mv1.w;
            const unsigned mb0 = (w0 >> (quad * 8)) & 0xFFu;
            const unsigned mb1 = (w1 >> (quad * 8)) & 0xFFu;

            float4 ga = *(const float4*)&gs[jb];
            float4 gb = *(const float4*)&gs[jb + 4];
            half8 aF0, aF1;
#pragma unroll
            for (int t = 0; t < 8; ++t) {
                float g = (t < 4) ? ((const float*)&ga)[t]
                                  : ((const float*)&gb)[t - 4];
                float s0 = fi0 + g; s0 = fmaxf(s0, ALPHA * s0);
                float s1 = fi1 + g; s1 = fmaxf(s1, ALPHA * s1);
                float p0 = ((mb0 >> t) & 1u) ? __expf(s0 - mi0) : 0.f;
                float p1 = ((mb1 >> t) & 1u) ? __expf(s1 - mi1) : 0.f;
                _Float16 h0 = (_Float16)p0, h1 = (_Float16)p1;
                aF0[t] = h0; aF1[t] = h1;
                psum0 += (float)h0; psum1 += (float)h1;
            }

            a00 = __builtin_amdgcn_mfma_f32_16x16x32_f16(aF0, b0, a00, 0, 0, 0);
            a01 = __builtin_amdgcn_mfma_f32_16x16x32_f16(aF0, b1, a01, 0, 0, 0);
            a02 = __builtin_amdgcn_mfma_f32_16x16x32_f16(aF0, b2, a02, 0, 0, 0);
            a03 = __builtin_amdgcn_mfma_f32_16x16x32_f16(aF0, b3, a03, 0, 0, 0);
            a10 = __builtin_amdgcn_mfma_f32_16x16x32_f16(aF1, b0, a10, 0, 0, 0);
            a11 = __builtin_amdgcn_mfma_f32_16x16x32_f16(aF1, b1, a11, 0, 0, 0);
            a12 = __builtin_amdgcn_mfma_f32_16x16x32_f16(aF1, b2, a12, 0, 0, 0);
            a13 = __builtin_amdgcn_mfma_f32_16x16x32_f16(aF1, b3, a13, 0, 0, 0);
        }
    }

    // ---- per-wave row sums (quads hold disjoint j's) ----
    psum0 += __shfl_xor(psum0, 16, 64);
    psum0 += __shfl_xor(psum0, 32, 64);
    psum1 += __shfl_xor(psum1, 16, 64);
    psum1 += __shfl_xor(psum1, 32, 64);
    if (lane < 16) {
        rsp[wsl * 32 + lane]      = psum0;
        rsp[wsl * 32 + 16 + lane] = psum1;
    }

    // ---- write partial C: C layout row = quad*4+reg, col = mrow ----
#pragma unroll
    for (int reg = 0; reg < 4; ++reg) {
        const int r0 = quad * 4 + reg;
        float* d0 = &redacc[(wsl * 32 + r0) * RSTR];
        d0[mrow]      = a00[reg];
        d0[16 + mrow] = a01[reg];
        d0[32 + mrow] = a02[reg];
        d0[48 + mrow] = a03[reg];
        float* d1 = &redacc[(wsl * 32 + 16 + r0) * RSTR];
        d1[mrow]      = a10[reg];
        d1[16 + mrow] = a11[reg];
        d1[32 + mrow] = a12[reg];
        d1[48 + mrow] = a13[reg];
    }
    __syncthreads();

    // ---- cross-wave reduce + normalize + store (coalesced) ----
    const int col  = tid & 63;
    const int rgrp = tid >> 6;
#pragma unroll
    for (int rr = 0; rr < 8; ++rr) {
        const int row = rgrp * 8 + rr;
        float sum = redacc[(row) * RSTR + col]
                  + redacc[(32 + row) * RSTR + col]
                  + redacc[(64 + row) * RSTR + col]
                  + redacc[(96 + row) * RSTR + col];
        float den = rsp[row] + rsp[32 + row] + rsp[64 + row] + rsp[96 + row];
        out[((size_t)b * N + i0 + row) * F_OUT + col] = sum / den;
    }
}

extern "C" void kernel_launch(void* const* d_in, const int* in_sizes, int n_in,
                              void* d_out, int out_size, void* d_ws, size_t ws_size,
                              hipStream_t stream) {
    const float* h   = (const float*)d_in[0];
    const float* adj = (const float*)d_in[1];
    const float* W   = (const float*)d_in[2];
    const float* a   = (const float*)d_in[3];
    float* out = (float*)d_out;

    char* ws = (char*)d_ws;
    _Float16* Wpack = (_Float16*)ws;                      // 2 MB
    float* fv = (float*)(ws + (size_t)B * F_OUT * N * 2); // 64 KB
    float* gv = fv + (size_t)B * N;                       // 64 KB
    unsigned* bits = (unsigned*)(gv + (size_t)B * N);     // 512 KB

    bitmask_kernel<<<dim3(N), 256, 0, stream>>>(adj, bits);
    wh_fg_t_kernel<<<dim3(B * N / 16), 256, 0, stream>>>(h, W, a, Wpack, fv, gv);
    attn_mfma_kernel<<<dim3(N / 32, B), 256, 0, stream>>>(Wpack, fv, gv, bits, out);
}

// Round 6
// 102.845 us; speedup vs baseline: 1.6516x; 1.1727x over previous
//
#include <hip/hip_runtime.h>
#include <hip/hip_bf16.h>
#include <math.h>

#define B 8
#define N 2048
#define F_IN 128
#define F_OUT 64
#define ALPHA 0.2f

typedef _Float16 half8 __attribute__((ext_vector_type(8)));
typedef float f32x4 __attribute__((ext_vector_type(4)));

// ---------------------------------------------------------------------------
// Kernel 1: adj -> bitmask. Block 0 additionally packs W into f16 MFMA
// B-fragment order (Wfrag) and computes wa1[k]=W[k,:]·a1, wa2[k]=W[k,:]·a2.
// ---------------------------------------------------------------------------
__global__ __launch_bounds__(256) void bitmask_kernel(
    const float* __restrict__ adj, unsigned* __restrict__ bits,
    const float* __restrict__ W, const float* __restrict__ a,
    _Float16* __restrict__ Wfrag, float* __restrict__ wa)
{
    const int i = blockIdx.x;
    const int tid = threadIdx.x;
    const int lane = tid & 63;
    const int w = tid >> 6;
    const float* row = adj + (size_t)i * N;
#pragma unroll
    for (int jt = 0; jt < 8; ++jt) {
        float v = row[jt * 256 + tid];
        unsigned long long m = __ballot(v > 0.f);
        if (lane == 0) {
            bits[i * 64 + jt * 8 + w * 2]     = (unsigned)m;
            bits[i * 64 + jt * 8 + w * 2 + 1] = (unsigned)(m >> 32);
        }
    }

    if (blockIdx.x == 0) {
        // W -> f16 fragment order: element (k,f) at
        //   Wfrag[((ks*4+fg)*64 + ((k>>3)&3)*16 + (f&15))*8 + (k&7)]
#pragma unroll
        for (int u = 0; u < 32; ++u) {
            int o    = tid * 32 + u;
            int slot = o & 7;
            int ln   = (o >> 3) & 63;
            int fg   = (o >> 9) & 3;
            int ks   = o >> 11;
            int k    = ks * 32 + (ln >> 4) * 8 + slot;
            int f    = fg * 16 + (ln & 15);
            Wfrag[o] = (_Float16)W[k * 64 + f];
        }
        // wa[0..127] = W @ a1, wa[128..255] = W @ a2 (fp32)
        const int k = tid & 127;
        const float* ap = a + (tid >> 7) * 64;
        float s = 0.f;
#pragma unroll
        for (int f = 0; f < 64; ++f) s += W[k * 64 + f] * ap[f];
        wa[(tid >> 7) * 128 + k] = s;
    }
}

// ---------------------------------------------------------------------------
// Kernel 2: Wh via MFMA (f16 in, fp32 acc), stored directly in Wpack fragment
// order; f/g computed fp32-exactly as h·(W a1), h·(W a2).
// 256 blocks x 64 rows; wave = one 16-row x 64-feature tile (16 MFMAs).
// ---------------------------------------------------------------------------
__global__ __launch_bounds__(256) void wh_fg_t_kernel(
    const float* __restrict__ h, const _Float16* __restrict__ Wfrag,
    const float* __restrict__ wa, _Float16* __restrict__ Wpack,
    float* __restrict__ fv, float* __restrict__ gv)
{
    const int tid  = threadIdx.x;
    const int w    = tid >> 6;
    const int lane = tid & 63;
    const int mrow = lane & 15;
    const int quad = lane >> 4;

    __shared__ float hs[64 * 132];   // 33.8 KB, pad 132 vs bank conflicts

    // stage 64 h-rows (32 KB) coalesced
    const float4* h4 = (const float4*)(h + (size_t)blockIdx.x * 64 * F_IN);
#pragma unroll
    for (int q = 0; q < 8; ++q) {
        int idx = q * 256 + tid;
        int r   = idx >> 5;
        int kq  = idx & 31;
        *(float4*)&hs[r * 132 + kq * 4] = h4[idx];
    }

    // W fragments: 16 coalesced half8 loads (L2-hot, independent of hs)
    half8 wF[4][4];
#pragma unroll
    for (int ks = 0; ks < 4; ++ks)
#pragma unroll
        for (int fg = 0; fg < 4; ++fg)
            wF[ks][fg] = *(const half8*)(Wfrag + (((ks * 4 + fg) * 64) + lane) * 8);

    __syncthreads();

    const int jgl = blockIdx.x * 64 + w * 16;  // global row of this wave's tile
    const int b   = jgl >> 11;
    const int jb  = jgl & (N - 1);
    const float* hrow = &hs[(w * 16 + mrow) * 132];

    // MFMA: A row = mrow (h-row), k = quad*8+t
    f32x4 acc0 = {0,0,0,0}, acc1 = {0,0,0,0}, acc2 = {0,0,0,0}, acc3 = {0,0,0,0};
#pragma unroll
    for (int ks = 0; ks < 4; ++ks) {
        const float* hp = hrow + ks * 32 + quad * 8;
        float4 x0 = *(const float4*)hp;
        float4 x1 = *(const float4*)(hp + 4);
        half8 aF;
#pragma unroll
        for (int t = 0; t < 4; ++t) {
            aF[t]     = (_Float16)((const float*)&x0)[t];
            aF[4 + t] = (_Float16)((const float*)&x1)[t];
        }
        acc0 = __builtin_amdgcn_mfma_f32_16x16x32_f16(aF, wF[ks][0], acc0, 0, 0, 0);
        acc1 = __builtin_amdgcn_mfma_f32_16x16x32_f16(aF, wF[ks][1], acc1, 0, 0, 0);
        acc2 = __builtin_amdgcn_mfma_f32_16x16x32_f16(aF, wF[ks][2], acc2, 0, 0, 0);
        acc3 = __builtin_amdgcn_mfma_f32_16x16x32_f16(aF, wF[ks][3], acc3, 0, 0, 0);
    }

    // f/g: row = mrow, k-chunk = quad*32 (fp32 exact)
    {
        const float* hp = hrow + quad * 32;
        const float* w1 = wa + quad * 32;
        const float* w2 = wa + 128 + quad * 32;
        float s1 = 0.f, s2 = 0.f;
#pragma unroll
        for (int t = 0; t < 32; ++t) {
            float hv = hp[t];
            s1 += hv * w1[t];
            s2 += hv * w2[t];
        }
        s1 += __shfl_xor(s1, 16, 64); s1 += __shfl_xor(s1, 32, 64);
        s2 += __shfl_xor(s2, 16, 64); s2 += __shfl_xor(s2, 32, 64);
        if (lane < 16) {
            fv[(size_t)b * N + jb + lane] = s1;
            gv[(size_t)b * N + jb + lane] = s2;
        }
    }

    // store Wpack: element (j = jb + quad*4 + reg, f = fg*16 + mrow)
    const int m     = jb >> 7;
    const int q     = (jb >> 5) & 3;
    const int jg    = (jb & 31) + quad * 4;
    const int flane = ((jg >> 3) & 3) * 16 + mrow;
    const int slot  = jg & 7;
    _Float16* base = Wpack + ((((size_t)b * 16 + m) * 4 + q) * 4) * 512
                     + (size_t)flane * 8 + slot;
    union { _Float16 hh[4]; ushort4 u; } pk;
#pragma unroll
    for (int reg = 0; reg < 4; ++reg) pk.hh[reg] = (_Float16)acc0[reg];
    *(ushort4*)(base)         = pk.u;
#pragma unroll
    for (int reg = 0; reg < 4; ++reg) pk.hh[reg] = (_Float16)acc1[reg];
    *(ushort4*)(base + 512)   = pk.u;
#pragma unroll
    for (int reg = 0; reg < 4; ++reg) pk.hh[reg] = (_Float16)acc2[reg];
    *(ushort4*)(base + 1024)  = pk.u;
#pragma unroll
    for (int reg = 0; reg < 4; ++reg) pk.hh[reg] = (_Float16)acc3[reg];
    *(ushort4*)(base + 1536)  = pk.u;
}

// ---------------------------------------------------------------------------
// Kernel 3: barrier-free MFMA aggregation (unchanged from round 5).
// ---------------------------------------------------------------------------
#define MSTR 68
#define RSTR 68

__global__ __launch_bounds__(256) void attn_mfma_kernel(
    const _Float16* __restrict__ Wpack, const float* __restrict__ fv,
    const float* __restrict__ gv, const unsigned* __restrict__ bits,
    float* __restrict__ out)
{
    const int i0 = blockIdx.x * 32;
    const int b  = blockIdx.y;
    const int tid  = threadIdx.x;
    const int lane = tid & 63;
    const int wsl  = tid >> 6;
    const int mrow = lane & 15;
    const int quad = lane >> 4;

    __shared__ __align__(16) float    gs[N];
    __shared__ float    fs[32];
    __shared__ float    ms[32];
    __shared__ __align__(16) unsigned mws[32 * MSTR];
    __shared__ float    redacc[4 * 32 * RSTR];
    __shared__ float    rsp[4 * 32];

    const float4* g4 = (const float4*)(gv + (size_t)b * N);
    ((float4*)gs)[tid]       = g4[tid];
    ((float4*)gs)[tid + 256] = g4[tid + 256];
    if (tid < 32) fs[tid] = fv[(size_t)b * N + i0 + tid];
#pragma unroll
    for (int s = 0; s < 2; ++s) {
        const int idx = tid + s * 256;
        const int i   = idx >> 4;
        const int w4  = (idx & 15) * 4;
        *(uint4*)&mws[i * MSTR + w4] =
            *(const uint4*)&bits[(size_t)(i0 + i) * 64 + w4];
    }
    __syncthreads();

#pragma unroll
    for (int rr = 0; rr < 2; ++rr) {
        const int ii = rr * 16 + (tid >> 4);
        const int jj = tid & 15;
        float gmax = -INFINITY;
#pragma unroll
        for (int t = 0; t < 4; ++t) {
            unsigned mw = mws[ii * MSTR + jj * 4 + t];
            const int jb = jj * 128 + t * 32;
            while (mw) {
                int bit = __builtin_ctz(mw);
                gmax = fmaxf(gmax, gs[jb + bit]);
                mw &= mw - 1;
            }
        }
#pragma unroll
        for (int off = 8; off >= 1; off >>= 1)
            gmax = fmaxf(gmax, __shfl_down(gmax, off, 16));
        if (jj == 0) {
            float m = fs[ii] + gmax;
            ms[ii] = (m > 0.f) ? m : ALPHA * m;
        }
    }
    __syncthreads();

    const float fi0 = fs[mrow],      mi0 = ms[mrow];
    const float fi1 = fs[16 + mrow], mi1 = ms[16 + mrow];
    const _Float16* wpb = Wpack + (size_t)b * 131072;

    f32x4 a00 = {0,0,0,0}, a01 = {0,0,0,0}, a02 = {0,0,0,0}, a03 = {0,0,0,0};
    f32x4 a10 = {0,0,0,0}, a11 = {0,0,0,0}, a12 = {0,0,0,0}, a13 = {0,0,0,0};
    float psum0 = 0.f, psum1 = 0.f;

    for (int mm = 0; mm < 4; ++mm) {
        const int m  = wsl * 4 + mm;
        const uint4 mv0 = *(const uint4*)&mws[mrow * MSTR + m * 4];
        const uint4 mv1 = *(const uint4*)&mws[(16 + mrow) * MSTR + m * 4];
#pragma unroll
        for (int q = 0; q < 4; ++q) {
            const int jb = m * 128 + q * 32 + quad * 8;
            const _Float16* tb = wpb + (size_t)(m * 4 + q) * 2048 + lane * 8;

            half8 b0 = *(const half8*)(tb);
            half8 b1 = *(const half8*)(tb + 512);
            half8 b2 = *(const half8*)(tb + 1024);
            half8 b3 = *(const half8*)(tb + 1536);

            const unsigned w0 = (q == 0) ? mv0.x : (q == 1) ? mv0.y
                               : (q == 2) ? mv0.z : mv0.w;
            const unsigned w1 = (q == 0) ? mv1.x : (q == 1) ? mv1.y
                               : (q == 2) ? mv1.z : mv1.w;
            const unsigned mb0 = (w0 >> (quad * 8)) & 0xFFu;
            const unsigned mb1 = (w1 >> (quad * 8)) & 0xFFu;

            float4 ga = *(const float4*)&gs[jb];
            float4 gb = *(const float4*)&gs[jb + 4];
            half8 aF0, aF1;
#pragma unroll
            for (int t = 0; t < 8; ++t) {
                float g = (t < 4) ? ((const float*)&ga)[t]
                                  : ((const float*)&gb)[t - 4];
                float s0 = fi0 + g; s0 = fmaxf(s0, ALPHA * s0);
                float s1 = fi1 + g; s1 = fmaxf(s1, ALPHA * s1);
                float p0 = ((mb0 >> t) & 1u) ? __expf(s0 - mi0) : 0.f;
                float p1 = ((mb1 >> t) & 1u) ? __expf(s1 - mi1) : 0.f;
                _Float16 h0 = (_Float16)p0, h1 = (_Float16)p1;
                aF0[t] = h0; aF1[t] = h1;
                psum0 += (float)h0; psum1 += (float)h1;
            }

            a00 = __builtin_amdgcn_mfma_f32_16x16x32_f16(aF0, b0, a00, 0, 0, 0);
            a01 = __builtin_amdgcn_mfma_f32_16x16x32_f16(aF0, b1, a01, 0, 0, 0);
            a02 = __builtin_amdgcn_mfma_f32_16x16x32_f16(aF0, b2, a02, 0, 0, 0);
            a03 = __builtin_amdgcn_mfma_f32_16x16x32_f16(aF0, b3, a03, 0, 0, 0);
            a10 = __builtin_amdgcn_mfma_f32_16x16x32_f16(aF1, b0, a10, 0, 0, 0);
            a11 = __builtin_amdgcn_mfma_f32_16x16x32_f16(aF1, b1, a11, 0, 0, 0);
            a12 = __builtin_amdgcn_mfma_f32_16x16x32_f16(aF1, b2, a12, 0, 0, 0);
            a13 = __builtin_amdgcn_mfma_f32_16x16x32_f16(aF1, b3, a13, 0, 0, 0);
        }
    }

    psum0 += __shfl_xor(psum0, 16, 64);
    psum0 += __shfl_xor(psum0, 32, 64);
    psum1 += __shfl_xor(psum1, 16, 64);
    psum1 += __shfl_xor(psum1, 32, 64);
    if (lane < 16) {
        rsp[wsl * 32 + lane]      = psum0;
        rsp[wsl * 32 + 16 + lane] = psum1;
    }

#pragma unroll
    for (int reg = 0; reg < 4; ++reg) {
        const int r0 = quad * 4 + reg;
        float* d0 = &redacc[(wsl * 32 + r0) * RSTR];
        d0[mrow]      = a00[reg];
        d0[16 + mrow] = a01[reg];
        d0[32 + mrow] = a02[reg];
        d0[48 + mrow] = a03[reg];
        float* d1 = &redacc[(wsl * 32 + 16 + r0) * RSTR];
        d1[mrow]      = a10[reg];
        d1[16 + mrow] = a11[reg];
        d1[32 + mrow] = a12[reg];
        d1[48 + mrow] = a13[reg];
    }
    __syncthreads();

    const int col  = tid & 63;
    const int rgrp = tid >> 6;
#pragma unroll
    for (int rr = 0; rr < 8; ++rr) {
        const int row = rgrp * 8 + rr;
        float sum = redacc[(row) * RSTR + col]
                  + redacc[(32 + row) * RSTR + col]
                  + redacc[(64 + row) * RSTR + col]
                  + redacc[(96 + row) * RSTR + col];
        float den = rsp[row] + rsp[32 + row] + rsp[64 + row] + rsp[96 + row];
        out[((size_t)b * N + i0 + row) * F_OUT + col] = sum / den;
    }
}

extern "C" void kernel_launch(void* const* d_in, const int* in_sizes, int n_in,
                              void* d_out, int out_size, void* d_ws, size_t ws_size,
                              hipStream_t stream) {
    const float* h   = (const float*)d_in[0];
    const float* adj = (const float*)d_in[1];
    const float* W   = (const float*)d_in[2];
    const float* a   = (const float*)d_in[3];
    float* out = (float*)d_out;

    char* ws = (char*)d_ws;
    _Float16* Wpack = (_Float16*)ws;                      // 2 MB
    float* fv = (float*)(ws + (size_t)B * F_OUT * N * 2); // 64 KB
    float* gv = fv + (size_t)B * N;                       // 64 KB
    unsigned* bits = (unsigned*)(gv + (size_t)B * N);     // 512 KB
    _Float16* Wfrag = (_Float16*)((char*)bits + (size_t)N * 64 * 4); // 16 KB
    float* wa = (float*)(Wfrag + 8192);                   // 1 KB

    bitmask_kernel<<<dim3(N), 256, 0, stream>>>(adj, bits, W, a, Wfrag, wa);
    wh_fg_t_kernel<<<dim3(B * N / 64), 256, 0, stream>>>(h, Wfrag, wa, Wpack, fv, gv);
    attn_mfma_kernel<<<dim3(N / 32, B), 256, 0, stream>>>(Wpack, fv, gv, bits, out);
}

// Round 7
// 102.064 us; speedup vs baseline: 1.6643x; 1.0077x over previous
//
#include <hip/hip_runtime.h>
#include <hip/hip_bf16.h>
#include <math.h>

#define B 8
#define N 2048
#define F_IN 128
#define F_OUT 64
#define ALPHA 0.2f

typedef _Float16 half8 __attribute__((ext_vector_type(8)));
typedef float f32x4 __attribute__((ext_vector_type(4)));

// ---------------------------------------------------------------------------
// Kernel 1: adj -> bitmask. Block 0 additionally packs W into f16 MFMA
// B-fragment order (Wfrag) and computes wa1[k]=W[k,:]·a1, wa2[k]=W[k,:]·a2.
// ---------------------------------------------------------------------------
__global__ __launch_bounds__(256) void bitmask_kernel(
    const float* __restrict__ adj, unsigned* __restrict__ bits,
    const float* __restrict__ W, const float* __restrict__ a,
    _Float16* __restrict__ Wfrag, float* __restrict__ wa)
{
    const int i = blockIdx.x;
    const int tid = threadIdx.x;
    const int lane = tid & 63;
    const int w = tid >> 6;
    const float* row = adj + (size_t)i * N;
#pragma unroll
    for (int jt = 0; jt < 8; ++jt) {
        float v = row[jt * 256 + tid];
        unsigned long long m = __ballot(v > 0.f);
        if (lane == 0) {
            bits[i * 64 + jt * 8 + w * 2]     = (unsigned)m;
            bits[i * 64 + jt * 8 + w * 2 + 1] = (unsigned)(m >> 32);
        }
    }

    if (blockIdx.x == 0) {
        // W -> f16 fragment order: element (k,f) at
        //   Wfrag[((ks*4+fg)*64 + ((k>>3)&3)*16 + (f&15))*8 + (k&7)]
#pragma unroll
        for (int u = 0; u < 32; ++u) {
            int o    = tid * 32 + u;
            int slot = o & 7;
            int ln   = (o >> 3) & 63;
            int fg   = (o >> 9) & 3;
            int ks   = o >> 11;
            int k    = ks * 32 + (ln >> 4) * 8 + slot;
            int f    = fg * 16 + (ln & 15);
            Wfrag[o] = (_Float16)W[k * 64 + f];
        }
        // wa[0..127] = W @ a1, wa[128..255] = W @ a2 (fp32)
        const int k = tid & 127;
        const float* ap = a + (tid >> 7) * 64;
        float s = 0.f;
#pragma unroll
        for (int f = 0; f < 64; ++f) s += W[k * 64 + f] * ap[f];
        wa[(tid >> 7) * 128 + k] = s;
    }
}

// ---------------------------------------------------------------------------
// Kernel 2: Wh via MFMA -> Wpack fragment order. 1024 blocks x 16 rows,
// 4 waves/block (wave = one 16-feature group, 4 MFMAs). High TLP: ~50 VGPR,
// 8.4 KB LDS -> 4 blocks/CU resident. f/g (fp32 exact) on wave 0.
// ---------------------------------------------------------------------------
__global__ __launch_bounds__(256) void wh_fg_t_kernel(
    const float* __restrict__ h, const _Float16* __restrict__ Wfrag,
    const float* __restrict__ wa, _Float16* __restrict__ Wpack,
    float* __restrict__ fv, float* __restrict__ gv)
{
    const int tid  = threadIdx.x;
    const int w    = tid >> 6;     // wave = feature group fg
    const int lane = tid & 63;
    const int mrow = lane & 15;
    const int quad = lane >> 4;

    __shared__ float hs[16 * 132];   // 8.4 KB, pad 132

    // stage 16 h-rows (8 KB) coalesced: 512 float4, 2 per thread
    const float4* h4 = (const float4*)(h + (size_t)blockIdx.x * 16 * F_IN);
#pragma unroll
    for (int s = 0; s < 2; ++s) {
        int idx = s * 256 + tid;
        *(float4*)&hs[(idx >> 5) * 132 + (idx & 31) * 4] = h4[idx];
    }

    // this wave's W fragments (4 x half8 = 16 VGPRs), L2-hot broadcast
    half8 wF[4];
#pragma unroll
    for (int ks = 0; ks < 4; ++ks)
        wF[ks] = *(const half8*)(Wfrag + (((ks * 4 + w) * 64) + lane) * 8);

    __syncthreads();

    const int jgl = blockIdx.x * 16;
    const int b   = jgl >> 11;
    const int jb  = jgl & (N - 1);
    const float* hrow = &hs[mrow * 132];

    // MFMA: A row = mrow (h-row), k = ks*32 + quad*8 + t
    f32x4 acc = {0.f, 0.f, 0.f, 0.f};
#pragma unroll
    for (int ks = 0; ks < 4; ++ks) {
        const float* hp = hrow + ks * 32 + quad * 8;
        float4 x0 = *(const float4*)hp;
        float4 x1 = *(const float4*)(hp + 4);
        half8 aF;
#pragma unroll
        for (int t = 0; t < 4; ++t) {
            aF[t]     = (_Float16)((const float*)&x0)[t];
            aF[4 + t] = (_Float16)((const float*)&x1)[t];
        }
        acc = __builtin_amdgcn_mfma_f32_16x16x32_f16(aF, wF[ks], acc, 0, 0, 0);
    }

    // f/g: wave 0 only; row = mrow, k-chunk = quad*32 (fp32 exact)
    if (w == 0) {
        const float* hp = hrow + quad * 32;
        const float* w1 = wa + quad * 32;
        const float* w2 = wa + 128 + quad * 32;
        float s1 = 0.f, s2 = 0.f;
#pragma unroll
        for (int t = 0; t < 32; ++t) {
            float hv = hp[t];
            s1 += hv * w1[t];
            s2 += hv * w2[t];
        }
        s1 += __shfl_xor(s1, 16, 64); s1 += __shfl_xor(s1, 32, 64);
        s2 += __shfl_xor(s2, 16, 64); s2 += __shfl_xor(s2, 32, 64);
        if (lane < 16) {
            fv[(size_t)b * N + jb + lane] = s1;
            gv[(size_t)b * N + jb + lane] = s2;
        }
    }

    // store Wpack: j = jb + quad*4 + reg, f = w*16 + mrow
    const int m     = jb >> 7;
    const int q     = (jb >> 5) & 3;
    const int jg    = (jb & 31) + quad * 4;
    const int flane = ((jg >> 3) & 3) * 16 + mrow;
    const int slot  = jg & 7;
    _Float16* base = Wpack + ((((size_t)b * 16 + m) * 4 + q) * 4 + w) * 512
                     + (size_t)flane * 8 + slot;
    union { _Float16 hh[4]; ushort4 u; } pk;
#pragma unroll
    for (int reg = 0; reg < 4; ++reg) pk.hh[reg] = (_Float16)acc[reg];
    *(ushort4*)(base) = pk.u;
}

// ---------------------------------------------------------------------------
// Kernel 3: barrier-free MFMA aggregation (unchanged from round 5/6).
// ---------------------------------------------------------------------------
#define MSTR 68
#define RSTR 68

__global__ __launch_bounds__(256) void attn_mfma_kernel(
    const _Float16* __restrict__ Wpack, const float* __restrict__ fv,
    const float* __restrict__ gv, const unsigned* __restrict__ bits,
    float* __restrict__ out)
{
    const int i0 = blockIdx.x * 32;
    const int b  = blockIdx.y;
    const int tid  = threadIdx.x;
    const int lane = tid & 63;
    const int wsl  = tid >> 6;
    const int mrow = lane & 15;
    const int quad = lane >> 4;

    __shared__ __align__(16) float    gs[N];
    __shared__ float    fs[32];
    __shared__ float    ms[32];
    __shared__ __align__(16) unsigned mws[32 * MSTR];
    __shared__ float    redacc[4 * 32 * RSTR];
    __shared__ float    rsp[4 * 32];

    const float4* g4 = (const float4*)(gv + (size_t)b * N);
    ((float4*)gs)[tid]       = g4[tid];
    ((float4*)gs)[tid + 256] = g4[tid + 256];
    if (tid < 32) fs[tid] = fv[(size_t)b * N + i0 + tid];
#pragma unroll
    for (int s = 0; s < 2; ++s) {
        const int idx = tid + s * 256;
        const int i   = idx >> 4;
        const int w4  = (idx & 15) * 4;
        *(uint4*)&mws[i * MSTR + w4] =
            *(const uint4*)&bits[(size_t)(i0 + i) * 64 + w4];
    }
    __syncthreads();

#pragma unroll
    for (int rr = 0; rr < 2; ++rr) {
        const int ii = rr * 16 + (tid >> 4);
        const int jj = tid & 15;
        float gmax = -INFINITY;
#pragma unroll
        for (int t = 0; t < 4; ++t) {
            unsigned mw = mws[ii * MSTR + jj * 4 + t];
            const int jb = jj * 128 + t * 32;
            while (mw) {
                int bit = __builtin_ctz(mw);
                gmax = fmaxf(gmax, gs[jb + bit]);
                mw &= mw - 1;
            }
        }
#pragma unroll
        for (int off = 8; off >= 1; off >>= 1)
            gmax = fmaxf(gmax, __shfl_down(gmax, off, 16));
        if (jj == 0) {
            float m = fs[ii] + gmax;
            ms[ii] = (m > 0.f) ? m : ALPHA * m;
        }
    }
    __syncthreads();

    const float fi0 = fs[mrow],      mi0 = ms[mrow];
    const float fi1 = fs[16 + mrow], mi1 = ms[16 + mrow];
    const _Float16* wpb = Wpack + (size_t)b * 131072;

    f32x4 a00 = {0,0,0,0}, a01 = {0,0,0,0}, a02 = {0,0,0,0}, a03 = {0,0,0,0};
    f32x4 a10 = {0,0,0,0}, a11 = {0,0,0,0}, a12 = {0,0,0,0}, a13 = {0,0,0,0};
    float psum0 = 0.f, psum1 = 0.f;

    for (int mm = 0; mm < 4; ++mm) {
        const int m  = wsl * 4 + mm;
        const uint4 mv0 = *(const uint4*)&mws[mrow * MSTR + m * 4];
        const uint4 mv1 = *(const uint4*)&mws[(16 + mrow) * MSTR + m * 4];
#pragma unroll
        for (int q = 0; q < 4; ++q) {
            const int jb = m * 128 + q * 32 + quad * 8;
            const _Float16* tb = wpb + (size_t)(m * 4 + q) * 2048 + lane * 8;

            half8 b0 = *(const half8*)(tb);
            half8 b1 = *(const half8*)(tb + 512);
            half8 b2 = *(const half8*)(tb + 1024);
            half8 b3 = *(const half8*)(tb + 1536);

            const unsigned w0 = (q == 0) ? mv0.x : (q == 1) ? mv0.y
                               : (q == 2) ? mv0.z : mv0.w;
            const unsigned w1 = (q == 0) ? mv1.x : (q == 1) ? mv1.y
                               : (q == 2) ? mv1.z : mv1.w;
            const unsigned mb0 = (w0 >> (quad * 8)) & 0xFFu;
            const unsigned mb1 = (w1 >> (quad * 8)) & 0xFFu;

            float4 ga = *(const float4*)&gs[jb];
            float4 gb = *(const float4*)&gs[jb + 4];
            half8 aF0, aF1;
#pragma unroll
            for (int t = 0; t < 8; ++t) {
                float g = (t < 4) ? ((const float*)&ga)[t]
                                  : ((const float*)&gb)[t - 4];
                float s0 = fi0 + g; s0 = fmaxf(s0, ALPHA * s0);
                float s1 = fi1 + g; s1 = fmaxf(s1, ALPHA * s1);
                float p0 = ((mb0 >> t) & 1u) ? __expf(s0 - mi0) : 0.f;
                float p1 = ((mb1 >> t) & 1u) ? __expf(s1 - mi1) : 0.f;
                _Float16 h0 = (_Float16)p0, h1 = (_Float16)p1;
                aF0[t] = h0; aF1[t] = h1;
                psum0 += (float)h0; psum1 += (float)h1;
            }

            a00 = __builtin_amdgcn_mfma_f32_16x16x32_f16(aF0, b0, a00, 0, 0, 0);
            a01 = __builtin_amdgcn_mfma_f32_16x16x32_f16(aF0, b1, a01, 0, 0, 0);
            a02 = __builtin_amdgcn_mfma_f32_16x16x32_f16(aF0, b2, a02, 0, 0, 0);
            a03 = __builtin_amdgcn_mfma_f32_16x16x32_f16(aF0, b3, a03, 0, 0, 0);
            a10 = __builtin_amdgcn_mfma_f32_16x16x32_f16(aF1, b0, a10, 0, 0, 0);
            a11 = __builtin_amdgcn_mfma_f32_16x16x32_f16(aF1, b1, a11, 0, 0, 0);
            a12 = __builtin_amdgcn_mfma_f32_16x16x32_f16(aF1, b2, a12, 0, 0, 0);
            a13 = __builtin_amdgcn_mfma_f32_16x16x32_f16(aF1, b3, a13, 0, 0, 0);
        }
    }

    psum0 += __shfl_xor(psum0, 16, 64);
    psum0 += __shfl_xor(psum0, 32, 64);
    psum1 += __shfl_xor(psum1, 16, 64);
    psum1 += __shfl_xor(psum1, 32, 64);
    if (lane < 16) {
        rsp[wsl * 32 + lane]      = psum0;
        rsp[wsl * 32 + 16 + lane] = psum1;
    }

#pragma unroll
    for (int reg = 0; reg < 4; ++reg) {
        const int r0 = quad * 4 + reg;
        float* d0 = &redacc[(wsl * 32 + r0) * RSTR];
        d0[mrow]      = a00[reg];
        d0[16 + mrow] = a01[reg];
        d0[32 + mrow] = a02[reg];
        d0[48 + mrow] = a03[reg];
        float* d1 = &redacc[(wsl * 32 + 16 + r0) * RSTR];
        d1[mrow]      = a10[reg];
        d1[16 + mrow] = a11[reg];
        d1[32 + mrow] = a12[reg];
        d1[48 + mrow] = a13[reg];
    }
    __syncthreads();

    const int col  = tid & 63;
    const int rgrp = tid >> 6;
#pragma unroll
    for (int rr = 0; rr < 8; ++rr) {
        const int row = rgrp * 8 + rr;
        float sum = redacc[(row) * RSTR + col]
                  + redacc[(32 + row) * RSTR + col]
                  + redacc[(64 + row) * RSTR + col]
                  + redacc[(96 + row) * RSTR + col];
        float den = rsp[row] + rsp[32 + row] + rsp[64 + row] + rsp[96 + row];
        out[((size_t)b * N + i0 + row) * F_OUT + col] = sum / den;
    }
}

extern "C" void kernel_launch(void* const* d_in, const int* in_sizes, int n_in,
                              void* d_out, int out_size, void* d_ws, size_t ws_size,
                              hipStream_t stream) {
    const float* h   = (const float*)d_in[0];
    const float* adj = (const float*)d_in[1];
    const float* W   = (const float*)d_in[2];
    const float* a   = (const float*)d_in[3];
    float* out = (float*)d_out;

    char* ws = (char*)d_ws;
    _Float16* Wpack = (_Float16*)ws;                      // 2 MB
    float* fv = (float*)(ws + (size_t)B * F_OUT * N * 2); // 64 KB
    float* gv = fv + (size_t)B * N;                       // 64 KB
    unsigned* bits = (unsigned*)(gv + (size_t)B * N);     // 512 KB
    _Float16* Wfrag = (_Float16*)((char*)bits + (size_t)N * 64 * 4); // 16 KB
    float* wa = (float*)(Wfrag + 8192);                   // 1 KB

    bitmask_kernel<<<dim3(N), 256, 0, stream>>>(adj, bits, W, a, Wfrag, wa);
    wh_fg_t_kernel<<<dim3(B * N / 16), 256, 0, stream>>>(h, Wfrag, wa, Wpack, fv, gv);
    attn_mfma_kernel<<<dim3(N / 32, B), 256, 0, stream>>>(Wpack, fv, gv, bits, out);
}